// Round 11
// baseline (181.711 us; speedup 1.0000x reference)
//
#include <hip/hip_runtime.h>
#include <hip/hip_bf16.h>
#include <stdint.h>

#define NH 16
#define SEQ 1024
#define EMB 1024
#define HDIM 64
#define BATCH 4
#define SPAD 1032  // strip row length in bf16 (1024 + 8 pad)

typedef float f32x4 __attribute__((ext_vector_type(4)));
typedef short bf16x8 __attribute__((ext_vector_type(8)));

static __device__ __forceinline__ short f2bf(float f) {
  union { float f; uint32_t u; } v; v.f = f;
  uint32_t r = (v.u + 0x7FFF + ((v.u >> 16) & 1)) >> 16;
  return (short)(uint16_t)r;
}
static __device__ __forceinline__ float bf2f(short h) {
  union { uint32_t u; float f; } v; v.u = ((uint32_t)(uint16_t)h) << 16;
  return v.f;
}

static __device__ __forceinline__ void gload_lds16(const void* g, void* l) {
  __builtin_amdgcn_global_load_lds(
      (const __attribute__((address_space(1))) void*)g,
      (__attribute__((address_space(3))) void*)l, 16, 0, 0);
}

// ---------- fp32 -> bf16 convert, 3 buffers fused ----------
static __device__ __forceinline__ void cvt8(const float* s, short* d) {
  const float4* sv = (const float4*)s;
  float4 a = sv[0], b = sv[1];
  bf16x8 o;
  o[0] = f2bf(a.x); o[1] = f2bf(a.y); o[2] = f2bf(a.z); o[3] = f2bf(a.w);
  o[4] = f2bf(b.x); o[5] = f2bf(b.y); o[6] = f2bf(b.z); o[7] = f2bf(b.w);
  *(bf16x8*)d = o;
}

__global__ void cvt3_kernel(const float* __restrict__ x, const float* __restrict__ w,
                            const float* __restrict__ o, short* __restrict__ xb,
                            short* __restrict__ wb, short* __restrict__ ob) {
  int i = (blockIdx.x * blockDim.x + threadIdx.x) * 8;
  if (i < 4194304) {
    cvt8(x + i, xb + i);
  } else if (i < 7340032) {
    cvt8(w + (i - 4194304), wb + (i - 4194304));
  } else {
    cvt8(o + (i - 7340032), ob + (i - 7340032));
  }
}

// ---------- V [bh][s][d] -> V^T [bh][d][s] (bf16, 64x64 LDS tiles) ----------
__global__ __launch_bounds__(256) void transpose_v(const short* __restrict__ v,
                                                   short* __restrict__ vt) {
  __shared__ short t[64][72];
  const int tid = threadIdx.x;
  const int bh = blockIdx.y;
  const int sb = blockIdx.x * 64;
  const int row = tid >> 2;        // 0..63
  const int c0 = (tid & 3) * 16;   // 0,16,32,48
  const short* src = v + ((size_t)(bh * SEQ + sb + row)) * HDIM + c0;
  *(bf16x8*)&t[row][c0] = *(const bf16x8*)src;
  *(bf16x8*)&t[row][c0 + 8] = *(const bf16x8*)(src + 8);
  __syncthreads();
  bf16x8 o0, o1;
#pragma unroll
  for (int i = 0; i < 8; ++i) o0[i] = t[c0 + i][row];
#pragma unroll
  for (int i = 0; i < 8; ++i) o1[i] = t[c0 + 8 + i][row];
  short* dst = vt + ((size_t)(bh * HDIM + row)) * SEQ + sb + c0;
  *(bf16x8*)dst = o0;
  *(bf16x8*)(dst + 8) = o1;
}

// ---------- 256x256x32 NT GEMM, 4-buffer deep pipeline, counted vmcnt ----------
// 512 threads = 8 waves (2M x 4N), each wave owns 128x64 of C.
// LDS: 4 bufs x (A 16KB + B 16KB) = 128 KB. Stage t+3 while computing t.
// K=1024 -> 32 K-tiles of BK=32 (R9 bug: only 16 were executed).
// Per wave 4 loads/K-tile; waits: vmcnt(8) steady, 8/4/0 at tail. One barrier
// per K-tile (32 MFMA/wave between barriers).
#define STAGEK(bb, kk0)                                                        \
  {                                                                            \
    int oo0 = w * 2048 + l * 16;                                               \
    int r0 = oo0 >> 6; int sc0 = (oo0 & 63) ^ ((r0 & 3) << 4);                 \
    int oo1 = oo0 + 1024;                                                      \
    int r1 = oo1 >> 6; int sc1 = (oo1 & 63) ^ ((r1 & 3) << 4);                 \
    gload_lds16((const char*)A + ((size_t)(row0 + r0) * K + (kk0)) * 2 + sc0,  \
                (char*)&As[(bb) * 8192] + w * 2048);                           \
    gload_lds16((const char*)A + ((size_t)(row0 + r1) * K + (kk0)) * 2 + sc1,  \
                (char*)&As[(bb) * 8192] + w * 2048 + 1024);                    \
    gload_lds16((const char*)Bm + ((size_t)(col0 + r0) * K + (kk0)) * 2 + sc0, \
                (char*)&Bs[(bb) * 8192] + w * 2048);                           \
    gload_lds16((const char*)Bm + ((size_t)(col0 + r1) * K + (kk0)) * 2 + sc1, \
                (char*)&Bs[(bb) * 8192] + w * 2048 + 1024);                    \
  }

#define KT(bb, DOSTAGE, t3, WAITN)                                             \
  {                                                                            \
    asm volatile("s_waitcnt vmcnt(" #WAITN ")" ::: "memory");                  \
    __builtin_amdgcn_s_barrier();                                              \
    asm volatile("" ::: "memory");                                             \
    bf16x8 af[8], bfr[4];                                                      \
    const short* Ab = &As[(bb) * 8192];                                        \
    const short* Bb = &Bs[(bb) * 8192];                                        \
    _Pragma("unroll") for (int i = 0; i < 8; ++i) {                            \
      int r = wr * 128 + i * 16 + l15;                                         \
      af[i] = *(const bf16x8*)((const char*)Ab + r * 64 +                      \
                               ((l4 * 16) ^ ((r & 3) << 4)));                  \
    }                                                                          \
    _Pragma("unroll") for (int j = 0; j < 4; ++j) {                            \
      int r = wc * 64 + j * 16 + l15;                                          \
      bfr[j] = *(const bf16x8*)((const char*)Bb + r * 64 +                     \
                                ((l4 * 16) ^ ((r & 3) << 4)));                 \
    }                                                                          \
    if (DOSTAGE) { STAGEK((t3) & 3, (t3) * 32); }                              \
    asm volatile("s_waitcnt lgkmcnt(0)" ::: "memory");                         \
    __builtin_amdgcn_sched_barrier(0);                                         \
    __builtin_amdgcn_s_setprio(1);                                             \
    _Pragma("unroll") for (int i = 0; i < 8; ++i)                              \
      _Pragma("unroll") for (int j = 0; j < 4; ++j)                            \
        acc[i][j] = __builtin_amdgcn_mfma_f32_16x16x32_bf16(af[i], bfr[j],     \
                                                            acc[i][j], 0, 0, 0); \
    __builtin_amdgcn_s_setprio(0);                                             \
  }

__global__ __launch_bounds__(512, 2) void gemm_qkv8(
    const short* __restrict__ A, const short* __restrict__ Bm,
    const float* __restrict__ bias, short* __restrict__ qkvws) {
  __shared__ short As[4 * 8192];
  __shared__ short Bs[4 * 8192];
  const int tid = threadIdx.x;
  const int w = tid >> 6, l = tid & 63;
  const int l15 = l & 15, l4 = l >> 4;
  const int wr = w >> 2, wc = w & 3;      // 2M x 4N wave grid
  const int row0 = blockIdx.x * 256;
  const int col0 = blockIdx.y * 256;
  const int K = EMB;

  f32x4 acc[8][4] = {};

  // prologue: 3 K-tiles in flight
  STAGEK(0, 0);
  STAGEK(1, 32);
  STAGEK(2, 64);

  // 32 K-tiles total: main loop stages t+3 = tiles 3..31
  for (int t = 0; t < 29; ++t) {
    KT(t & 3, 1, t + 3, 8);
  }
  KT(1, 0, 0, 8);   // t=29 (29&3==1)
  KT(2, 0, 0, 4);   // t=30
  KT(3, 0, 0, 0);   // t=31

  // epilogue: scatter bf16 to Q/K/V [bh][s][d]
#pragma unroll
  for (int j = 0; j < 4; ++j) {
    int f = col0 + wc * 64 + j * 16 + l15;
    float bv = bias[f];
    int part = f >> 10;               // 0=Q 1=K 2=V
    int e = f & 1023;
    int hh = e >> 6, d = e & 63;
#pragma unroll
    for (int mi = 0; mi < 8; ++mi) {
#pragma unroll
      for (int rr = 0; rr < 4; ++rr) {
        int m = row0 + wr * 128 + mi * 16 + l4 * 4 + rr;
        int bb2 = m >> 10, ss = m & 1023;
        qkvws[(size_t)part * 4194304 +
              ((size_t)(bb2 * NH + hh) * SEQ + ss) * HDIM + d] =
            f2bf(acc[mi][j][rr] + bv);
      }
    }
  }
}

// ---------- 128x64x32 NT GEMM for out-proj, dbuf, 24 KB LDS ----------
#define STAGE_OUT(bb, kk0)                                                     \
  {                                                                            \
    _Pragma("unroll") for (int c = 0; c < 2; ++c) {                            \
      int oo = oA + c * 1024;                                                  \
      int row = oo >> 6;                                                       \
      int scol = (oo & 63) ^ ((row & 3) << 4);                                 \
      gload_lds16((const char*)A + ((size_t)(row0 + row) * K + (kk0)) * 2 + scol, \
                  (char*)As[bb] + (w * 2 + c) * 1024);                         \
    }                                                                          \
    {                                                                          \
      int oo = oB;                                                             \
      int row = oo >> 6;                                                       \
      int scol = (oo & 63) ^ ((row & 3) << 4);                                 \
      gload_lds16((const char*)Bm + ((size_t)(col0 + row) * K + (kk0)) * 2 + scol,\
                  (char*)Bs[bb] + w * 1024);                                   \
    }                                                                          \
  }

#define COMPUTE_OUT(bb)                                                        \
  {                                                                            \
    bf16x8 af[2], bfr[4];                                                      \
    const int kbo = (l4 * 16) ^ ((l15 & 3) << 4);                              \
    _Pragma("unroll") for (int i = 0; i < 2; ++i)                              \
      af[i] = *(const bf16x8*)((const char*)As[bb] + (w * 32 + i * 16 + l15) * 64 + kbo); \
    _Pragma("unroll") for (int j = 0; j < 4; ++j)                              \
      bfr[j] = *(const bf16x8*)((const char*)Bs[bb] + (j * 16 + l15) * 64 + kbo); \
    _Pragma("unroll") for (int i = 0; i < 2; ++i)                              \
      _Pragma("unroll") for (int j = 0; j < 4; ++j)                            \
        acc[i][j] = __builtin_amdgcn_mfma_f32_16x16x32_bf16(af[i], bfr[j], acc[i][j], 0, 0, 0); \
  }

__global__ __launch_bounds__(256) void gemm_out64(
    const short* __restrict__ A, const short* __restrict__ Bm,
    const float* __restrict__ bias, float* __restrict__ outp) {
  __shared__ short As[2][128 * 32];
  __shared__ short Bs[2][64 * 32];
  const int tid = threadIdx.x;
  const int w = tid >> 6, l = tid & 63;
  const int l15 = l & 15, l4 = l >> 4;
  const int row0 = blockIdx.x * 128;
  const int col0 = blockIdx.y * 64;
  const int K = EMB;

  f32x4 acc[2][4] = {};

  const int oA = (w * 2) * 1024 + l * 16;
  const int oB = w * 1024 + l * 16;
  STAGE_OUT(0, 0);
  __syncthreads();

  int cur = 0;
  for (int k0 = 0; k0 < K; k0 += 32) {
    if (k0 + 32 < K) STAGE_OUT(cur ^ 1, k0 + 32);
    COMPUTE_OUT(cur);
    __syncthreads();
    cur ^= 1;
  }

#pragma unroll
  for (int j = 0; j < 4; ++j) {
    int f = col0 + j * 16 + l15;
    float bv = bias[f];
#pragma unroll
    for (int i = 0; i < 2; ++i)
#pragma unroll
      for (int rr = 0; rr < 4; ++rr) {
        int m = row0 + w * 32 + i * 16 + l4 * 4 + rr;
        __builtin_nontemporal_store(acc[i][j][rr] + bv, &outp[(size_t)m * EMB + f]);
      }
  }
}

// ---------- fused attention per (b,h, 32-row block); 2 blocks/CU ----------
__global__ __launch_bounds__(256) void attn_kernel(
    const short* __restrict__ qws, const short* __restrict__ kws,
    const short* __restrict__ vtws, float* __restrict__ attg,
    short* __restrict__ aow) {
  __shared__ short strip[32 * SPAD];  // unnormalized exp(scores), bf16 (66 KB)
  __shared__ float wsum[4][32];
  __shared__ float inv_sum[32];

  const int tid = threadIdx.x;
  const int w = tid >> 6, l = tid & 63;
  const int l15 = l & 15, l4 = l >> 4;
  const int blk = blockIdx.x;
  const int bh = blk >> 5;       // 0..63
  const int r = blk & 31;        // 32-row block index
  const int rowbase = r * 32;

  const short* qb = qws + ((size_t)bh * SEQ + rowbase) * HDIM;
  const short* kb = kws + (size_t)bh * SEQ * HDIM;
  const short* vb = vtws + (size_t)bh * HDIM * SEQ;

  bf16x8 qf[2][2];
#pragma unroll
  for (int rg = 0; rg < 2; ++rg)
#pragma unroll
    for (int ks = 0; ks < 2; ++ks)
      qf[rg][ks] = *(const bf16x8*)(qb + (rg * 16 + l15) * HDIM + ks * 32 + l4 * 8);

  const int ngroups = (rowbase + 32) >> 4;  // 2r+2 groups of 16 cols (even)
  float psum[2][4] = {};

  for (int g = w; g < ngroups; g += 4) {
    const short* kg = kb + (g * 16 + l15) * HDIM + l4 * 8;
    bf16x8 kf0 = *(const bf16x8*)(kg);
    bf16x8 kf1 = *(const bf16x8*)(kg + 32);
    f32x4 a0 = {}, a1 = {};
    a0 = __builtin_amdgcn_mfma_f32_16x16x32_bf16(qf[0][0], kf0, a0, 0, 0, 0);
    a0 = __builtin_amdgcn_mfma_f32_16x16x32_bf16(qf[0][1], kf1, a0, 0, 0, 0);
    a1 = __builtin_amdgcn_mfma_f32_16x16x32_bf16(qf[1][0], kf0, a1, 0, 0, 0);
    a1 = __builtin_amdgcn_mfma_f32_16x16x32_bf16(qf[1][1], kf1, a1, 0, 0, 0);
    int col = g * 16 + l15;
#pragma unroll
    for (int rg = 0; rg < 2; ++rg) {
#pragma unroll
      for (int rr = 0; rr < 4; ++rr) {
        int rloc = rg * 16 + l4 * 4 + rr;
        int row = rowbase + rloc;
        float sv = (rg ? a1[rr] : a0[rr]) * 0.125f;
        float ev = (col <= row) ? __expf(sv) : 0.0f;
        psum[rg][rr] += ev;
        strip[rloc * SPAD + col] = f2bf(ev);
      }
    }
  }

#pragma unroll
  for (int rg = 0; rg < 2; ++rg)
#pragma unroll
    for (int rr = 0; rr < 4; ++rr) {
      float v = psum[rg][rr];
      v += __shfl_xor(v, 1);
      v += __shfl_xor(v, 2);
      v += __shfl_xor(v, 4);
      v += __shfl_xor(v, 8);
      psum[rg][rr] = v;
    }
  if (l15 == 0) {
#pragma unroll
    for (int rg = 0; rg < 2; ++rg)
#pragma unroll
      for (int rr = 0; rr < 4; ++rr)
        wsum[w][rg * 16 + l4 * 4 + rr] = psum[rg][rr];
  }
  __syncthreads();
  if (tid < 32) {
    float s = wsum[0][tid] + wsum[1][tid] + wsum[2][tid] + wsum[3][tid];
    inv_sum[tid] = 1.0f / s;
  }
  __syncthreads();

  // write normalized att (full 1024 cols; zeros beyond causal limit), NT stores
  {
    const int limit = ngroups * 16;
    const int rloc = tid >> 3;
    const int cb = tid & 7;
    float* arow = attg + (size_t)bh * SEQ * SEQ + (size_t)(rowbase + rloc) * SEQ;
    float isr = inv_sum[rloc];
#pragma unroll
    for (int i = 0; i < 16; ++i) {
      int c = (cb + i * 8) * 8;
      f32x4 o0, o1;
      if (c < limit) {
        bf16x8 p = *(const bf16x8*)&strip[rloc * SPAD + c];
        o0[0] = bf2f(p[0]) * isr; o0[1] = bf2f(p[1]) * isr;
        o0[2] = bf2f(p[2]) * isr; o0[3] = bf2f(p[3]) * isr;
        o1[0] = bf2f(p[4]) * isr; o1[1] = bf2f(p[5]) * isr;
        o1[2] = bf2f(p[6]) * isr; o1[3] = bf2f(p[7]) * isr;
      } else {
        o0 = (f32x4)0.0f;
        o1 = (f32x4)0.0f;
      }
      __builtin_nontemporal_store(o0, (f32x4*)(arow + c));
      __builtin_nontemporal_store(o1, (f32x4*)(arow + c + 4));
    }
  }

  // PV: out[32 x 64] from strip (unnormalized) x V^T, scale rows by inv_sum
  {
    const int nch = ngroups >> 1;  // r+1 chunks of 32 keys
    const int d0 = w * 16;
    f32x4 oacc[2] = {};
    const short* vrow = vb + (d0 + l15) * SEQ + l4 * 8;
    for (int c = 0; c < nch; ++c) {
      bf16x8 vf = *(const bf16x8*)(vrow + c * 32);
      bf16x8 p0 = *(const bf16x8*)&strip[(0 + l15) * SPAD + c * 32 + l4 * 8];
      bf16x8 p1 = *(const bf16x8*)&strip[(16 + l15) * SPAD + c * 32 + l4 * 8];
      oacc[0] = __builtin_amdgcn_mfma_f32_16x16x32_bf16(p0, vf, oacc[0], 0, 0, 0);
      oacc[1] = __builtin_amdgcn_mfma_f32_16x16x32_bf16(p1, vf, oacc[1], 0, 0, 0);
    }
    const int b = bh >> 4, h = bh & 15;
#pragma unroll
    for (int rg = 0; rg < 2; ++rg) {
#pragma unroll
      for (int rr = 0; rr < 4; ++rr) {
        int rloc = rg * 16 + l4 * 4 + rr;
        int s = rowbase + rloc;
        float v = oacc[rg][rr] * inv_sum[rloc];
        aow[((size_t)(b * SEQ + s)) * EMB + h * HDIM + d0 + l15] = f2bf(v);
      }
    }
  }
}

extern "C" void kernel_launch(void* const* d_in, const int* in_sizes, int n_in,
                              void* d_out, int out_size, void* d_ws, size_t ws_size,
                              hipStream_t stream) {
  (void)in_sizes; (void)n_in; (void)out_size; (void)ws_size;
  const float* x = (const float*)d_in[0];
  const float* ipw = (const float*)d_in[2];
  const float* ipb = (const float*)d_in[3];
  const float* ow = (const float*)d_in[4];
  const float* ob = (const float*)d_in[5];
  float* outp = (float*)d_out;
  float* attg = (float*)d_out + (size_t)BATCH * SEQ * EMB;

  char* ws = (char*)d_ws;
  short* xbf = (short*)(ws);                   //  8,388,608 B (dead after QKV gemm)
  short* wbf = (short*)(ws + 8388608);         //  6,291,456 B
  short* owbf = (short*)(ws + 14680064);       //  2,097,152 B
  short* qkvws = (short*)(ws + 16777216);      // 25,165,824 B  (Q | K | V, [bh][s][d])
  short* aow = (short*)(ws + 41943040);        //  8,388,608 B -> 50,331,648 total
  short* vtws = (short*)(ws);                  // aliases xbf (dead by transpose time)

  short* qws = qkvws;
  short* kws = qkvws + 4194304;
  short* vws = qkvws + 8388608;

  cvt3_kernel<<<4096, 256, 0, stream>>>(x, ipw, ow, xbf, wbf, owbf);

  dim3 g1(16, 12);
  gemm_qkv8<<<g1, 512, 0, stream>>>(xbf, wbf, ipb, qkvws);

  transpose_v<<<dim3(16, 64), 256, 0, stream>>>(vws, vtws);

  attn_kernel<<<2048, 256, 0, stream>>>(qws, kws, vtws, attg, aow);

  gemm_out64<<<dim3(32, 16), 256, 0, stream>>>(aow, owbf, ob, outp);
}

// Round 12
// 150.817 us; speedup vs baseline: 1.2048x; 1.2048x over previous
//
#include <hip/hip_runtime.h>
#include <hip/hip_bf16.h>
#include <stdint.h>

#define NH 16
#define SEQ 1024
#define EMB 1024
#define HDIM 64
#define BATCH 4
#define SPAD 1032  // strip row length in bf16 (1024 + 8 pad)

typedef float f32x4 __attribute__((ext_vector_type(4)));
typedef short bf16x8 __attribute__((ext_vector_type(8)));
typedef short bf16x4 __attribute__((ext_vector_type(4)));

static __device__ __forceinline__ short f2bf(float f) {
  union { float f; uint32_t u; } v; v.f = f;
  uint32_t r = (v.u + 0x7FFF + ((v.u >> 16) & 1)) >> 16;
  return (short)(uint16_t)r;
}
static __device__ __forceinline__ float bf2f(short h) {
  union { uint32_t u; float f; } v; v.u = ((uint32_t)(uint16_t)h) << 16;
  return v.f;
}

static __device__ __forceinline__ void gload_lds16(const void* g, void* l) {
  __builtin_amdgcn_global_load_lds(
      (const __attribute__((address_space(1))) void*)g,
      (__attribute__((address_space(3))) void*)l, 16, 0, 0);
}

// ---------- fp32 -> bf16 convert, 3 buffers fused ----------
static __device__ __forceinline__ void cvt8(const float* s, short* d) {
  const float4* sv = (const float4*)s;
  float4 a = sv[0], b = sv[1];
  bf16x8 o;
  o[0] = f2bf(a.x); o[1] = f2bf(a.y); o[2] = f2bf(a.z); o[3] = f2bf(a.w);
  o[4] = f2bf(b.x); o[5] = f2bf(b.y); o[6] = f2bf(b.z); o[7] = f2bf(b.w);
  *(bf16x8*)d = o;
}

__global__ void cvt3_kernel(const float* __restrict__ x, const float* __restrict__ w,
                            const float* __restrict__ o, short* __restrict__ xb,
                            short* __restrict__ wb, short* __restrict__ ob) {
  int i = (blockIdx.x * blockDim.x + threadIdx.x) * 8;
  if (i < 4194304) {
    cvt8(x + i, xb + i);
  } else if (i < 7340032) {
    cvt8(w + (i - 4194304), wb + (i - 4194304));
  } else {
    cvt8(o + (i - 7340032), ob + (i - 7340032));
  }
}

// ---------- V [bh][s][d] -> V^T [bh][d][s] (bf16, 64x64 LDS tiles) ----------
__global__ __launch_bounds__(256) void transpose_v(const short* __restrict__ v,
                                                   short* __restrict__ vt) {
  __shared__ short t[64][72];
  const int tid = threadIdx.x;
  const int bh = blockIdx.y;
  const int sb = blockIdx.x * 64;
  const int row = tid >> 2;        // 0..63
  const int c0 = (tid & 3) * 16;   // 0,16,32,48
  const short* src = v + ((size_t)(bh * SEQ + sb + row)) * HDIM + c0;
  *(bf16x8*)&t[row][c0] = *(const bf16x8*)src;
  *(bf16x8*)&t[row][c0 + 8] = *(const bf16x8*)(src + 8);
  __syncthreads();
  bf16x8 o0, o1;
#pragma unroll
  for (int i = 0; i < 8; ++i) o0[i] = t[c0 + i][row];
#pragma unroll
  for (int i = 0; i < 8; ++i) o1[i] = t[c0 + 8 + i][row];
  short* dst = vt + ((size_t)(bh * HDIM + row)) * SEQ + sb + c0;
  *(bf16x8*)dst = o0;
  *(bf16x8*)(dst + 8) = o1;
}

// ---------- 128x128x32 NT GEMM, dbuf, 32 KB LDS -> 3 blocks/CU (R8 proven) ----------
#define STAGE_QKV(bb, kk0)                                                     \
  {                                                                            \
    _Pragma("unroll") for (int c = 0; c < 2; ++c) {                            \
      int oo = o + c * 1024;                                                   \
      int row = oo >> 6;                                                       \
      int scol = (oo & 63) ^ ((row & 3) << 4);                                 \
      gload_lds16((const char*)A + ((size_t)(row0 + row) * K + (kk0)) * 2 + scol, \
                  (char*)As[bb] + (w * 2 + c) * 1024);                         \
      gload_lds16((const char*)Bm + ((size_t)(col0 + row) * K + (kk0)) * 2 + scol,\
                  (char*)Bs[bb] + (w * 2 + c) * 1024);                         \
    }                                                                          \
  }

#define COMPUTE_QKV(bb)                                                        \
  {                                                                            \
    bf16x8 af[4], bfr[4];                                                      \
    const int kbo = (l4 * 16) ^ ((l15 & 3) << 4);                              \
    _Pragma("unroll") for (int i = 0; i < 4; ++i) {                            \
      af[i] = *(const bf16x8*)((const char*)As[bb] + (wr * 64 + i * 16 + l15) * 64 + kbo); \
      bfr[i] = *(const bf16x8*)((const char*)Bs[bb] + (wc * 64 + i * 16 + l15) * 64 + kbo); \
    }                                                                          \
    _Pragma("unroll") for (int i = 0; i < 4; ++i)                              \
      _Pragma("unroll") for (int j = 0; j < 4; ++j)                            \
        acc[i][j] = __builtin_amdgcn_mfma_f32_16x16x32_bf16(af[i], bfr[j], acc[i][j], 0, 0, 0); \
  }

__global__ __launch_bounds__(256) void gemm_qkv(
    const short* __restrict__ A, const short* __restrict__ Bm,
    const float* __restrict__ bias, short* __restrict__ qkvws) {
  __shared__ short As[2][128 * 32];
  __shared__ short Bs[2][128 * 32];
  const int tid = threadIdx.x;
  const int w = tid >> 6, l = tid & 63;
  const int l15 = l & 15, l4 = l >> 4;
  const int wr = w >> 1, wc = w & 1;
  const int row0 = blockIdx.x * 128;
  const int col0 = blockIdx.y * 128;
  const int K = EMB;

  f32x4 acc[4][4] = {};

  const int o = (w * 2) * 1024 + l * 16;
  STAGE_QKV(0, 0);
  __syncthreads();

  int cur = 0;
  for (int k0 = 0; k0 < K; k0 += 32) {
    if (k0 + 32 < K) STAGE_QKV(cur ^ 1, k0 + 32);
    COMPUTE_QKV(cur);
    __syncthreads();
    cur ^= 1;
  }

#pragma unroll
  for (int j = 0; j < 4; ++j) {
    int f = col0 + wc * 64 + j * 16 + l15;
    float bv = bias[f];
    int part = f >> 10;               // 0=Q 1=K 2=V
    int e = f & 1023;
    int hh = e >> 6, d = e & 63;
#pragma unroll
    for (int i = 0; i < 4; ++i) {
#pragma unroll
      for (int rr = 0; rr < 4; ++rr) {
        int m = row0 + wr * 64 + i * 16 + l4 * 4 + rr;
        int bb = m >> 10, ss = m & 1023;
        qkvws[(size_t)part * 4194304 +
              ((size_t)(bb * NH + hh) * SEQ + ss) * HDIM + d] =
            f2bf(acc[i][j][rr] + bv);
      }
    }
  }
}

// ---------- 128x64x32 NT GEMM for out-proj, dbuf, 24 KB LDS ----------
#define STAGE_OUT(bb, kk0)                                                     \
  {                                                                            \
    _Pragma("unroll") for (int c = 0; c < 2; ++c) {                            \
      int oo = oA + c * 1024;                                                  \
      int row = oo >> 6;                                                       \
      int scol = (oo & 63) ^ ((row & 3) << 4);                                 \
      gload_lds16((const char*)A + ((size_t)(row0 + row) * K + (kk0)) * 2 + scol, \
                  (char*)As[bb] + (w * 2 + c) * 1024);                         \
    }                                                                          \
    {                                                                          \
      int oo = oB;                                                             \
      int row = oo >> 6;                                                       \
      int scol = (oo & 63) ^ ((row & 3) << 4);                                 \
      gload_lds16((const char*)Bm + ((size_t)(col0 + row) * K + (kk0)) * 2 + scol,\
                  (char*)Bs[bb] + w * 1024);                                   \
    }                                                                          \
  }

#define COMPUTE_OUT(bb)                                                        \
  {                                                                            \
    bf16x8 af[2], bfr[4];                                                      \
    const int kbo = (l4 * 16) ^ ((l15 & 3) << 4);                              \
    _Pragma("unroll") for (int i = 0; i < 2; ++i)                              \
      af[i] = *(const bf16x8*)((const char*)As[bb] + (w * 32 + i * 16 + l15) * 64 + kbo); \
    _Pragma("unroll") for (int j = 0; j < 4; ++j)                              \
      bfr[j] = *(const bf16x8*)((const char*)Bs[bb] + (j * 16 + l15) * 64 + kbo); \
    _Pragma("unroll") for (int i = 0; i < 2; ++i)                              \
      _Pragma("unroll") for (int j = 0; j < 4; ++j)                            \
        acc[i][j] = __builtin_amdgcn_mfma_f32_16x16x32_bf16(af[i], bfr[j], acc[i][j], 0, 0, 0); \
  }

__global__ __launch_bounds__(256) void gemm_out64(
    const short* __restrict__ A, const short* __restrict__ Bm,
    const float* __restrict__ bias, float* __restrict__ outp) {
  __shared__ short As[2][128 * 32];
  __shared__ short Bs[2][64 * 32];
  const int tid = threadIdx.x;
  const int w = tid >> 6, l = tid & 63;
  const int l15 = l & 15, l4 = l >> 4;
  const int row0 = blockIdx.x * 128;
  const int col0 = blockIdx.y * 64;
  const int K = EMB;

  f32x4 acc[2][4] = {};

  const int oA = (w * 2) * 1024 + l * 16;
  const int oB = w * 1024 + l * 16;
  STAGE_OUT(0, 0);
  __syncthreads();

  int cur = 0;
  for (int k0 = 0; k0 < K; k0 += 32) {
    if (k0 + 32 < K) STAGE_OUT(cur ^ 1, k0 + 32);
    COMPUTE_OUT(cur);
    __syncthreads();
    cur ^= 1;
  }

#pragma unroll
  for (int j = 0; j < 4; ++j) {
    int f = col0 + j * 16 + l15;
    float bv = bias[f];
#pragma unroll
    for (int i = 0; i < 2; ++i)
#pragma unroll
      for (int rr = 0; rr < 4; ++rr) {
        int m = row0 + w * 32 + i * 16 + l4 * 4 + rr;
        __builtin_nontemporal_store(acc[i][j][rr] + bv, &outp[(size_t)m * EMB + f]);
      }
  }
}

// ---------- fused attention per (b,h, 32-row block); 2 blocks/CU ----------
// R11: zero-writes hoisted before the reduction (drain under barrier latency);
// att-write merged into the PV loop per 32-col chunk (stores interleave MFMA).
__global__ __launch_bounds__(256) void attn_kernel(
    const short* __restrict__ qws, const short* __restrict__ kws,
    const short* __restrict__ vtws, float* __restrict__ attg,
    short* __restrict__ aow) {
  __shared__ short strip[32 * SPAD];  // unnormalized exp(scores), bf16 (66 KB)
  __shared__ float wsum[4][32];
  __shared__ float inv_sum[32];

  const int tid = threadIdx.x;
  const int w = tid >> 6, l = tid & 63;
  const int l15 = l & 15, l4 = l >> 4;
  const int blk = blockIdx.x;
  const int bh = blk >> 5;       // 0..63
  const int r = blk & 31;        // 32-row block index
  const int rowbase = r * 32;

  const short* qb = qws + ((size_t)bh * SEQ + rowbase) * HDIM;
  const short* kb = kws + (size_t)bh * SEQ * HDIM;
  const short* vb = vtws + (size_t)bh * HDIM * SEQ;
  float* ablk = attg + (size_t)bh * SEQ * SEQ + (size_t)rowbase * SEQ;

  bf16x8 qf[2][2];
#pragma unroll
  for (int rg = 0; rg < 2; ++rg)
#pragma unroll
    for (int ks = 0; ks < 2; ++ks)
      qf[rg][ks] = *(const bf16x8*)(qb + (rg * 16 + l15) * HDIM + ks * 32 + l4 * 8);

  const int ngroups = (rowbase + 32) >> 4;  // 2r+2 groups of 16 cols (even)
  const int limit = ngroups * 16;           // causal cols (multiple of 32)
  float psum[2][4] = {};

  for (int g = w; g < ngroups; g += 4) {
    const short* kg = kb + (g * 16 + l15) * HDIM + l4 * 8;
    bf16x8 kf0 = *(const bf16x8*)(kg);
    bf16x8 kf1 = *(const bf16x8*)(kg + 32);
    f32x4 a0 = {}, a1 = {};
    a0 = __builtin_amdgcn_mfma_f32_16x16x32_bf16(qf[0][0], kf0, a0, 0, 0, 0);
    a0 = __builtin_amdgcn_mfma_f32_16x16x32_bf16(qf[0][1], kf1, a0, 0, 0, 0);
    a1 = __builtin_amdgcn_mfma_f32_16x16x32_bf16(qf[1][0], kf0, a1, 0, 0, 0);
    a1 = __builtin_amdgcn_mfma_f32_16x16x32_bf16(qf[1][1], kf1, a1, 0, 0, 0);
    int col = g * 16 + l15;
#pragma unroll
    for (int rg = 0; rg < 2; ++rg) {
#pragma unroll
      for (int rr = 0; rr < 4; ++rr) {
        int rloc = rg * 16 + l4 * 4 + rr;
        int row = rowbase + rloc;
        float sv = (rg ? a1[rr] : a0[rr]) * 0.125f;
        float ev = (col <= row) ? __expf(sv) : 0.0f;
        psum[rg][rr] += ev;
        strip[rloc * SPAD + col] = f2bf(ev);
      }
    }
  }

  // upper-triangle zeros: independent of softmax -> issue now, drain under
  // the reduction barriers. rows x [limit, 1024) in f32x4 units.
  {
    const int rloc = tid >> 3;
    const int cb = tid & 7;
    float* arow = ablk + (size_t)rloc * SEQ;
    const f32x4 z = (f32x4)0.0f;
    for (int c = limit + cb * 4; c < SEQ; c += 32)
      __builtin_nontemporal_store(z, (f32x4*)(arow + c));
  }

#pragma unroll
  for (int rg = 0; rg < 2; ++rg)
#pragma unroll
    for (int rr = 0; rr < 4; ++rr) {
      float v = psum[rg][rr];
      v += __shfl_xor(v, 1);
      v += __shfl_xor(v, 2);
      v += __shfl_xor(v, 4);
      v += __shfl_xor(v, 8);
      psum[rg][rr] = v;
    }
  if (l15 == 0) {
#pragma unroll
    for (int rg = 0; rg < 2; ++rg)
#pragma unroll
      for (int rr = 0; rr < 4; ++rr)
        wsum[w][rg * 16 + l4 * 4 + rr] = psum[rg][rr];
  }
  __syncthreads();
  if (tid < 32) {
    float s = wsum[0][tid] + wsum[1][tid] + wsum[2][tid] + wsum[3][tid];
    inv_sum[tid] = 1.0f / s;
  }
  __syncthreads();

  // merged PV + att-write loop over 32-col chunks: 2 MFMA + 1 f32x4 store
  // per thread per chunk -> stores drain under MFMA.
  {
    const int nch = ngroups >> 1;  // r+1 chunks of 32 cols
    const int d0 = w * 16;
    const int wrloc = tid >> 3;        // att-write row 0..31
    const int wcb = tid & 7;           // att-write col-slot
    const float wisr = inv_sum[wrloc];
    float* warow = ablk + (size_t)wrloc * SEQ;
    f32x4 oacc[2] = {};
    const short* vrow = vb + (d0 + l15) * SEQ + l4 * 8;
    for (int c = 0; c < nch; ++c) {
      bf16x8 vf = *(const bf16x8*)(vrow + c * 32);
      bf16x8 p0 = *(const bf16x8*)&strip[(0 + l15) * SPAD + c * 32 + l4 * 8];
      bf16x8 p1 = *(const bf16x8*)&strip[(16 + l15) * SPAD + c * 32 + l4 * 8];
      oacc[0] = __builtin_amdgcn_mfma_f32_16x16x32_bf16(p0, vf, oacc[0], 0, 0, 0);
      oacc[1] = __builtin_amdgcn_mfma_f32_16x16x32_bf16(p1, vf, oacc[1], 0, 0, 0);
      {
        int col = c * 32 + wcb * 4;
        bf16x4 pw = *(const bf16x4*)&strip[wrloc * SPAD + col];
        f32x4 ov;
        ov[0] = bf2f(pw[0]) * wisr; ov[1] = bf2f(pw[1]) * wisr;
        ov[2] = bf2f(pw[2]) * wisr; ov[3] = bf2f(pw[3]) * wisr;
        __builtin_nontemporal_store(ov, (f32x4*)(warow + col));
      }
    }
    const int b = bh >> 4, h = bh & 15;
#pragma unroll
    for (int rg = 0; rg < 2; ++rg) {
#pragma unroll
      for (int rr = 0; rr < 4; ++rr) {
        int rloc = rg * 16 + l4 * 4 + rr;
        int s = rowbase + rloc;
        float v = oacc[rg][rr] * inv_sum[rloc];
        aow[((size_t)(b * SEQ + s)) * EMB + h * HDIM + d0 + l15] = f2bf(v);
      }
    }
  }
}

extern "C" void kernel_launch(void* const* d_in, const int* in_sizes, int n_in,
                              void* d_out, int out_size, void* d_ws, size_t ws_size,
                              hipStream_t stream) {
  (void)in_sizes; (void)n_in; (void)out_size; (void)ws_size;
  const float* x = (const float*)d_in[0];
  const float* ipw = (const float*)d_in[2];
  const float* ipb = (const float*)d_in[3];
  const float* ow = (const float*)d_in[4];
  const float* ob = (const float*)d_in[5];
  float* outp = (float*)d_out;
  float* attg = (float*)d_out + (size_t)BATCH * SEQ * EMB;

  char* ws = (char*)d_ws;
  short* xbf = (short*)(ws);                   //  8,388,608 B (dead after QKV gemm)
  short* wbf = (short*)(ws + 8388608);         //  6,291,456 B
  short* owbf = (short*)(ws + 14680064);       //  2,097,152 B
  short* qkvws = (short*)(ws + 16777216);      // 25,165,824 B  (Q | K | V, [bh][s][d])
  short* aow = (short*)(ws + 41943040);        //  8,388,608 B -> 50,331,648 total
  short* vtws = (short*)(ws);                  // aliases xbf (dead by transpose time)

  short* qws = qkvws;
  short* kws = qkvws + 4194304;
  short* vws = qkvws + 8388608;

  cvt3_kernel<<<4096, 256, 0, stream>>>(x, ipw, ow, xbf, wbf, owbf);

  dim3 g1(32, 24);
  gemm_qkv<<<g1, 256, 0, stream>>>(xbf, wbf, ipb, qkvws);

  transpose_v<<<dim3(16, 64), 256, 0, stream>>>(vws, vtws);

  attn_kernel<<<2048, 256, 0, stream>>>(qws, kws, vtws, attg, aow);

  gemm_out64<<<dim3(32, 16), 256, 0, stream>>>(aow, owbf, ob, outp);
}